// Round 1
// baseline (421.955 us; speedup 1.0000x reference)
//
#include <hip/hip_runtime.h>
#include <stdint.h>

typedef uint16_t u16;
typedef __attribute__((ext_vector_type(8))) short s8v;      // 8 x bf16 MFMA frag
typedef __attribute__((ext_vector_type(4))) float f32x4;
typedef __attribute__((ext_vector_type(4))) unsigned short us4;

__device__ __forceinline__ float bf2f(u16 u) {
  union { uint32_t i; float f; } x; x.i = ((uint32_t)u) << 16; return x.f;
}
__device__ __forceinline__ u16 f2bf(float f) {
  union { float f; uint32_t i; } x; x.f = f;
  uint32_t r = (x.i + 0x7FFFu + ((x.i >> 16) & 1u)) >> 16;
  return (u16)r;
}

// ---------------- GroupNorm stats: one block per (n,g), 8192 contiguous floats ----
__global__ __launch_bounds__(256) void gn_stats_kernel(const float* __restrict__ x,
                                                       float2* __restrict__ stats) {
  const int tid = threadIdx.x;
  const float* p = x + (long)blockIdx.x * 8192;
  float s = 0.f, s2 = 0.f;
#pragma unroll
  for (int it = 0; it < 8; ++it) {
    float4 v = *(const float4*)(p + it * 1024 + tid * 4);
    s  += v.x + v.y + v.z + v.w;
    s2 += v.x * v.x + v.y * v.y + v.z * v.z + v.w * v.w;
  }
#pragma unroll
  for (int off = 32; off >= 1; off >>= 1) {
    s  += __shfl_down(s, off);
    s2 += __shfl_down(s2, off);
  }
  __shared__ float ps[4], ps2[4];
  const int wv = tid >> 6, lane = tid & 63;
  if (lane == 0) { ps[wv] = s; ps2[wv] = s2; }
  __syncthreads();
  if (tid == 0) {
    float S1 = ps[0] + ps[1] + ps[2] + ps[3];
    float S2 = ps2[0] + ps2[1] + ps2[2] + ps2[3];
    float mean = S1 * (1.f / 8192.f);
    float var = S2 * (1.f / 8192.f) - mean * mean;
    stats[blockIdx.x] = make_float2(mean, rsqrtf(var + 1e-6f));
  }
}

// ---------------- GroupNorm apply + transpose: writes hfT[n][p][c] bf16 ------------
__global__ __launch_bounds__(256) void gn_apply_kernel(const float* __restrict__ x,
                                                       const float2* __restrict__ stats,
                                                       const float* __restrict__ gamma,
                                                       const float* __restrict__ beta,
                                                       u16* __restrict__ hfT) {
  const int pt = blockIdx.x, n = blockIdx.y;
  __shared__ u16 lds[64][264];
  const int tid = threadIdx.x;
  const float* xb = x + (long)n * 262144 + pt * 64;
#pragma unroll
  for (int it = 0; it < 16; ++it) {
    int idx = it * 256 + tid;
    int c = idx >> 4, pv = idx & 15;
    float4 v = *(const float4*)(xb + (long)c * 1024 + pv * 4);
    float2 st = stats[n * 32 + (c >> 3)];
    float ga = gamma[c], be = beta[c];
    lds[pv * 4 + 0][c] = f2bf((v.x - st.x) * st.y * ga + be);
    lds[pv * 4 + 1][c] = f2bf((v.y - st.x) * st.y * ga + be);
    lds[pv * 4 + 2][c] = f2bf((v.z - st.x) * st.y * ga + be);
    lds[pv * 4 + 3][c] = f2bf((v.w - st.x) * st.y * ga + be);
  }
  __syncthreads();
  u16* dst = hfT + (long)n * 262144 + (long)pt * 64 * 256;
#pragma unroll
  for (int it = 0; it < 16; ++it) {
    int idx = it * 256 + tid;
    int pp = idx >> 6, cv = idx & 63;
    us4 o;
#pragma unroll
    for (int j = 0; j < 4; ++j) o[j] = lds[pp][cv * 4 + j];
    *(us4*)(dst + pp * 256 + cv * 4) = o;
  }
}

// ---------------- Generic bf16-MFMA GEMM, 64x64x64 tile, 4 waves ------------------
// D[m][n] = alpha * sum_k a(m,k) b(k,n) (+bias[m]|bias[n]) (+resid) ; out f32/f32+= /bf16
// AKM: A stored [K][M] (else [M][K]) ; BKN: B stored [K][N] (else [N][K])
template <int AF32, int AKM, int BF32, int BKN, int BIAS, int RES, int OUTM>
__global__ __launch_bounds__(256) void gemm_kernel(
    const void* __restrict__ Ap, const void* __restrict__ Bp,
    const float* __restrict__ bias, const float* __restrict__ resid,
    void* __restrict__ Dp, int K, int ldA, long sA, int ldB, long sB,
    int ldD, long sD, long sRes, float alpha) {
  constexpr int LDT = 72;  // 64 + 8 pad (bf16) keeps ds_read_b128 2-way max
  __shared__ u16 Asm[64 * LDT];
  __shared__ u16 Bsm[64 * LDT];
  const int tid = threadIdx.x;
  const int wv = tid >> 6, lane = tid & 63, lhi = lane >> 4, llo = lane & 15;
  const int m0 = blockIdx.y * 64, n0 = blockIdx.x * 64;
  const int bz = blockIdx.z;

  f32x4 acc[4] = {};

  const int nK = K >> 6;
  for (int kt = 0; kt < nK; ++kt) {
    const int k0 = kt * 64;
    __syncthreads();
    // ---- stage A -> Asm[m][k]
#pragma unroll
    for (int it = 0; it < 4; ++it) {
      int idx = it * 256 + tid;
      if (AKM == 0) {
        int m = idx >> 4, kv = idx & 15;
        if (AF32) {
          float4 v = *(const float4*)((const float*)Ap + (long)bz * sA + (long)(m0 + m) * ldA + k0 + kv * 4);
          u16* d = &Asm[m * LDT + kv * 4];
          d[0] = f2bf(v.x); d[1] = f2bf(v.y); d[2] = f2bf(v.z); d[3] = f2bf(v.w);
        } else {
          us4 v = *(const us4*)((const u16*)Ap + (long)bz * sA + (long)(m0 + m) * ldA + k0 + kv * 4);
          *(us4*)&Asm[m * LDT + kv * 4] = v;
        }
      } else {
        int kk = idx >> 4, mv = idx & 15;
        if (AF32) {
          float4 v = *(const float4*)((const float*)Ap + (long)bz * sA + (long)(k0 + kk) * ldA + m0 + mv * 4);
          Asm[(mv * 4 + 0) * LDT + kk] = f2bf(v.x);
          Asm[(mv * 4 + 1) * LDT + kk] = f2bf(v.y);
          Asm[(mv * 4 + 2) * LDT + kk] = f2bf(v.z);
          Asm[(mv * 4 + 3) * LDT + kk] = f2bf(v.w);
        } else {
          us4 v = *(const us4*)((const u16*)Ap + (long)bz * sA + (long)(k0 + kk) * ldA + m0 + mv * 4);
#pragma unroll
          for (int j = 0; j < 4; ++j) Asm[(mv * 4 + j) * LDT + kk] = v[j];
        }
      }
    }
    // ---- stage B -> Bsm[n][k]
#pragma unroll
    for (int it = 0; it < 4; ++it) {
      int idx = it * 256 + tid;
      if (BKN == 0) {
        int nn = idx >> 4, kv = idx & 15;
        if (BF32) {
          float4 v = *(const float4*)((const float*)Bp + (long)bz * sB + (long)(n0 + nn) * ldB + k0 + kv * 4);
          u16* d = &Bsm[nn * LDT + kv * 4];
          d[0] = f2bf(v.x); d[1] = f2bf(v.y); d[2] = f2bf(v.z); d[3] = f2bf(v.w);
        } else {
          us4 v = *(const us4*)((const u16*)Bp + (long)bz * sB + (long)(n0 + nn) * ldB + k0 + kv * 4);
          *(us4*)&Bsm[nn * LDT + kv * 4] = v;
        }
      } else {
        int kk = idx >> 4, nv = idx & 15;
        if (BF32) {
          float4 v = *(const float4*)((const float*)Bp + (long)bz * sB + (long)(k0 + kk) * ldB + n0 + nv * 4);
          Bsm[(nv * 4 + 0) * LDT + kk] = f2bf(v.x);
          Bsm[(nv * 4 + 1) * LDT + kk] = f2bf(v.y);
          Bsm[(nv * 4 + 2) * LDT + kk] = f2bf(v.z);
          Bsm[(nv * 4 + 3) * LDT + kk] = f2bf(v.w);
        } else {
          us4 v = *(const us4*)((const u16*)Bp + (long)bz * sB + (long)(k0 + kk) * ldB + n0 + nv * 4);
#pragma unroll
          for (int j = 0; j < 4; ++j) Bsm[(nv * 4 + j) * LDT + kk] = v[j];
        }
      }
    }
    __syncthreads();
    // ---- MFMA: wave wv owns rows [wv*16, wv*16+16), all 64 cols (4 frags)
#pragma unroll
    for (int kk = 0; kk < 2; ++kk) {
      const int ko = kk * 32 + lhi * 8;
      s8v a = *(const s8v*)&Asm[(wv * 16 + llo) * LDT + ko];
#pragma unroll
      for (int nf = 0; nf < 4; ++nf) {
        s8v b = *(const s8v*)&Bsm[(nf * 16 + llo) * LDT + ko];
        acc[nf] = __builtin_amdgcn_mfma_f32_16x16x32_bf16(a, b, acc[nf], 0, 0, 0);
      }
    }
  }
  // ---- epilogue: D row = m0+wv*16+lhi*4+r, col = n0+nf*16+llo
#pragma unroll
  for (int nf = 0; nf < 4; ++nf) {
    const int col = n0 + nf * 16 + llo;
    float bn_ = (BIAS == 2) ? bias[col] : 0.f;
#pragma unroll
    for (int r = 0; r < 4; ++r) {
      const int row = m0 + wv * 16 + lhi * 4 + r;
      float val = acc[nf][r] * alpha + bn_;
      if (BIAS == 1) val += bias[row];
      long off = (long)bz * sD + (long)row * ldD + col;
      if (RES) val += resid[(long)bz * sRes + (long)row * ldD + col];
      if (OUTM == 0)      ((float*)Dp)[off] = val;
      else if (OUTM == 1) ((float*)Dp)[off] += val;
      else                ((u16*)Dp)[off] = f2bf(val);
    }
  }
}

// ---------------- row softmax in-place on bf16 S, one wave per row of 1024 --------
__global__ __launch_bounds__(64) void softmax_kernel(u16* __restrict__ S) {
  u16* p = S + (long)blockIdx.x * 1024;
  const int lane = threadIdx.x;
  float v[16];
#pragma unroll
  for (int it = 0; it < 4; ++it) {
    us4 u = *(const us4*)(p + (it * 64 + lane) * 4);
#pragma unroll
    for (int j = 0; j < 4; ++j) v[it * 4 + j] = bf2f(u[j]);
  }
  float mx = -3.4e38f;
#pragma unroll
  for (int i = 0; i < 16; ++i) mx = fmaxf(mx, v[i]);
#pragma unroll
  for (int off = 32; off >= 1; off >>= 1) mx = fmaxf(mx, __shfl_xor(mx, off));
  float sum = 0.f;
#pragma unroll
  for (int i = 0; i < 16; ++i) { v[i] = __expf(v[i] - mx); sum += v[i]; }
#pragma unroll
  for (int off = 32; off >= 1; off >>= 1) sum += __shfl_xor(sum, off);
  float inv = 1.f / sum;
#pragma unroll
  for (int it = 0; it < 4; ++it) {
    us4 o;
#pragma unroll
    for (int j = 0; j < 4; ++j) o[j] = f2bf(v[it * 4 + j] * inv);
    *(us4*)(p + (it * 64 + lane) * 4) = o;
  }
}

// ---------------- temporal axial attention: block per (b,hw), 8 heads, T=16 -------
__global__ __launch_bounds__(256) void tattn_kernel(const u16* __restrict__ qt,
                                                    const u16* __restrict__ kt,
                                                    const u16* __restrict__ vt,
                                                    u16* __restrict__ ot) {
  const int bi = blockIdx.x >> 10, hw = blockIdx.x & 1023;
  const long base = (long)bi * 4194304 + (long)hw * 256;
  __shared__ float qs[16][260], ks[16][260], vs[16][260];
  __shared__ u16 os[16][256];
  const int tid = threadIdx.x;
#pragma unroll
  for (int it = 0; it < 4; ++it) {
    int idx = it * 256 + tid;
    int t = idx >> 6, cv = idx & 63;
    long g = base + (long)t * 262144 + cv * 4;
    us4 a = *(const us4*)(qt + g);
    us4 b = *(const us4*)(kt + g);
    us4 c = *(const us4*)(vt + g);
#pragma unroll
    for (int j = 0; j < 4; ++j) {
      qs[t][cv * 4 + j] = bf2f(a[j]);
      ks[t][cv * 4 + j] = bf2f(b[j]);
      vs[t][cv * 4 + j] = bf2f(c[j]);
    }
  }
  __syncthreads();
  if (tid < 128) {
    const int h = tid >> 4, t = tid & 15;
    const int c0 = h * 32;
    float sc[16];
    float mx = -3.4e38f;
#pragma unroll
    for (int t2 = 0; t2 < 16; ++t2) {
      float d = 0.f;
#pragma unroll
      for (int dd = 0; dd < 32; ++dd) d += qs[t][c0 + dd] * ks[t2][c0 + dd];
      sc[t2] = d * 0.17677669529663687f;  // 1/sqrt(32)
      mx = fmaxf(mx, sc[t2]);
    }
    float sum = 0.f;
#pragma unroll
    for (int t2 = 0; t2 < 16; ++t2) { sc[t2] = __expf(sc[t2] - mx); sum += sc[t2]; }
    float inv = 1.f / sum;
#pragma unroll
    for (int dd = 0; dd < 32; ++dd) {
      float o = 0.f;
#pragma unroll
      for (int t2 = 0; t2 < 16; ++t2) o += sc[t2] * vs[t2][c0 + dd];
      os[t][c0 + dd] = f2bf(o * inv);
    }
  }
  __syncthreads();
#pragma unroll
  for (int it = 0; it < 4; ++it) {
    int idx = it * 256 + tid;
    int t = idx >> 6, cv = idx & 63;
    us4 o4;
#pragma unroll
    for (int j = 0; j < 4; ++j) o4[j] = os[t][cv * 4 + j];
    *(us4*)(ot + base + (long)t * 262144 + cv * 4) = o4;
  }
}

// =================================================================================
extern "C" void kernel_launch(void* const* d_in, const int* in_sizes, int n_in,
                              void* d_out, int out_size, void* d_ws, size_t ws_size,
                              hipStream_t stream) {
  const float* x     = (const float*)d_in[0];
  const float* gam   = (const float*)d_in[1];
  const float* bet   = (const float*)d_in[2];
  const float* wq_s  = (const float*)d_in[3];
  const float* bq_s  = (const float*)d_in[4];
  const float* wk_s  = (const float*)d_in[5];
  const float* bk_s  = (const float*)d_in[6];
  const float* wv_s  = (const float*)d_in[7];
  const float* bv_s  = (const float*)d_in[8];
  const float* wo_s  = (const float*)d_in[9];
  const float* bo_s  = (const float*)d_in[10];
  const float* wq_t  = (const float*)d_in[11];
  const float* wk_t  = (const float*)d_in[12];
  const float* wv_t  = (const float*)d_in[13];
  const float* wf_t  = (const float*)d_in[14];
  const float* bf_t  = (const float*)d_in[15];
  float* out = (float*)d_out;

  // ws layout (bf16 u16 buffers). Spatial live set, temporal aliases dead spatial.
  u16* hfT  = (u16*)d_ws;           // [32][1024][256]
  u16* qb   = hfT + 8388608;        // [32][1024][256]  q[n][p][c]
  u16* kb   = qb + 8388608;         // [32][1024][256]  k[n][p][c] (=k_ref^T)
  u16* vb   = kb + 8388608;         // [32][256][1024]  v[n][c][p]
  u16* attb = vb + 8388608;         // [32][1024][256]  att[n][p][c]
  u16* Sb   = attb + 8388608;       // [32][1024][1024]
  float2* stats = (float2*)(Sb + 33554432);
  u16* qt = hfT; u16* kt = qb; u16* vt = kb; u16* ot = vb;  // temporal aliases

  gn_stats_kernel<<<1024, 256, 0, stream>>>(x, stats);
  gn_apply_kernel<<<dim3(16, 32), 256, 0, stream>>>(x, stats, gam, bet, hfT);
  // q,k: D[p][o] = hfT[p][c] . W[o][c] + b[o]   (A bf16 MK, B f32 NK, bias N, bf16)
  gemm_kernel<0,0,1,0,2,0,2><<<dim3(4,16,32),256,0,stream>>>(hfT, wq_s, bq_s, nullptr, qb, 256, 256, 262144L, 256, 0L, 256, 262144L, 0L, 1.f);
  gemm_kernel<0,0,1,0,2,0,2><<<dim3(4,16,32),256,0,stream>>>(hfT, wk_s, bk_s, nullptr, kb, 256, 256, 262144L, 256, 0L, 256, 262144L, 0L, 1.f);
  // v: D[o][p] = W[o][c] . hfT[p][c] + b[o]     (A f32 MK, B bf16 NK, bias M, bf16)
  gemm_kernel<1,0,0,0,1,0,2><<<dim3(16,4,32),256,0,stream>>>(wv_s, hfT, bv_s, nullptr, vb, 256, 256, 0L, 256, 262144L, 1024, 262144L, 0L, 1.f);
  // S: D[i][j] = q[i][c] . k[j][c] / 16         (bf16 MK x bf16 NK, bf16 out)
  gemm_kernel<0,0,0,0,0,0,2><<<dim3(16,16,32),256,0,stream>>>(qb, kb, nullptr, nullptr, Sb, 256, 256, 262144L, 256, 262144L, 1024, 1048576L, 0L, 0.0625f);
  softmax_kernel<<<32768, 64, 0, stream>>>(Sb);
  // PV: att[i][c] = P[i][j] . v[c][j]           (bf16 MK x bf16 NK, K=1024, bf16)
  gemm_kernel<0,0,0,0,0,0,2><<<dim3(4,16,32),256,0,stream>>>(Sb, vb, nullptr, nullptr, attb, 1024, 1024, 1048576L, 1024, 262144L, 256, 262144L, 0L, 1.f);
  // proj: out[n][o][p] = x + bo[o] + wo[o][c] . att[p][c]  (f32 out, residual)
  gemm_kernel<1,0,0,0,1,1,0><<<dim3(16,4,32),256,0,stream>>>(wo_s, attb, bo_s, x, out, 256, 256, 0L, 256, 262144L, 1024, 262144L, 262144L, 1.f);
  // temporal qkv: D[s][o] = x[b][c][s] . W[c][o]  (A f32 KM, B f32 KN, bf16 out)
  gemm_kernel<1,1,1,1,0,0,2><<<dim3(4,256,2),256,0,stream>>>(x, wq_t, nullptr, nullptr, qt, 256, 16384, 4194304L, 256, 0L, 256, 4194304L, 0L, 1.f);
  gemm_kernel<1,1,1,1,0,0,2><<<dim3(4,256,2),256,0,stream>>>(x, wk_t, nullptr, nullptr, kt, 256, 16384, 4194304L, 256, 0L, 256, 4194304L, 0L, 1.f);
  gemm_kernel<1,1,1,1,0,0,2><<<dim3(4,256,2),256,0,stream>>>(x, wv_t, nullptr, nullptr, vt, 256, 16384, 4194304L, 256, 0L, 256, 4194304L, 0L, 1.f);
  tattn_kernel<<<2048, 256, 0, stream>>>(qt, kt, vt, ot);
  // final: out[b][o][s] += bf[o] + wf_t[c][o] . ot[s][c]  (f32 accumulate)
  gemm_kernel<1,1,0,0,1,0,1><<<dim3(256,4,2),256,0,stream>>>(wf_t, ot, bf_t, nullptr, out, 256, 256, 0L, 256, 4194304L, 16384, 4194304L, 0L, 1.f);
}